// Round 6
// baseline (157.184 us; speedup 1.0000x reference)
//
#include <hip/hip_runtime.h>

typedef __attribute__((ext_vector_type(8))) short short8;
typedef __attribute__((ext_vector_type(4))) float f32x4;

#define CM 256
#define CC 32
#define CZ 128
#define SDIM 128
#define IDIM 256

__device__ __forceinline__ unsigned short f2bf(float f) {
  union { float f; unsigned u; } v; v.f = f;
  unsigned r = v.u + 0x7fffu + ((v.u >> 16) & 1u);
  return (unsigned short)(r >> 16);
}
// pack two f32 -> two bf16 (round-half-up; 1 add each + 2 ops to merge)
__device__ __forceinline__ unsigned pack_bf2(float a, float b) {
  union { float f; unsigned u; } x, y; x.f = a; y.f = b;
  return ((x.u + 0x8000u) >> 16) | ((y.u + 0x8000u) & 0xffff0000u);
}

// ---------------- kernel 0: weight prep ----------------
// wlrT[c64][e]  (c64<32: w_left col, else w_right col), bf16, [64][256]
// WF fragment-major: WF[((zt*32+ks)*64+lane)*8+e]; lane(qd,ln) holds
//   W[z=zt*16+ln][kappa=ks*32+qd*8+e]/128, kappa=d*32+c (d=ks, c=qd*8+e)
__global__ void k_prep(const float* __restrict__ wl, const float* __restrict__ wr,
                       const float* __restrict__ wo,
                       unsigned short* __restrict__ wlrT, unsigned short* __restrict__ WF) {
  int t = blockIdx.x * 256 + threadIdx.x;
  if (t < 64 * 256) {
    int c = t >> 8, e = t & 255;
    float v = (c < CC) ? wl[e * CC + c] : wr[e * CC + (c - CC)];
    wlrT[c * 256 + e] = f2bf(v);
  } else {
    int t2 = t - 64 * 256;
    if (t2 < 8 * 32 * 64) {
      int zt = t2 >> 11, ks = (t2 >> 6) & 31, lane = t2 & 63;
      int ln = lane & 15, qd = lane >> 4;
      int z = zt * 16 + ln;
#pragma unroll
      for (int e = 0; e < 8; ++e) {
        int c = qd * 8 + e, d = ks;
        WF[(size_t)t2 * 8 + e] = f2bf(wo[(c * 32 + d) * CZ + z] * (1.0f / 128.0f));
      }
    }
  }
}

// ---------------- kernel 1: LayerNorm + dual projection ----------------
// One block per i (256 blocks x 512 threads). Outputs:
//   A2 fragment-major: A2[((rt*4+ks)*64+lane)*8+e] = A[rt*16+ln][ks*32+qd*8+e]
//   Bbuf row-major:    Bbuf[(i*32+d)*128 + s]
__global__ __launch_bounds__(512) void k_lnproj(
    const float* __restrict__ x, const float* __restrict__ lnw, const float* __restrict__ lnb,
    const float* __restrict__ bl, const float* __restrict__ br,
    const unsigned short* __restrict__ wlrT,
    unsigned short* __restrict__ A2, unsigned short* __restrict__ Bbuf) {
  extern __shared__ __align__(16) char lds[];
  unsigned short* xn = (unsigned short*)lds;            // [128 s][264] = 67,584 B
  unsigned short* sT = (unsigned short*)(lds + 67584);  // [64 c64][136] = 17,408 B
  int tid = threadIdx.x;
  int lane = tid & 63, ww = tid >> 6;
  int qd = lane >> 4, ln = lane & 15;
  int i = blockIdx.x;

  for (int rr = 0; rr < 16; ++rr) {
    int s = ww * 16 + rr;
    float4 v = ((const float4*)(x + ((size_t)s * IDIM + i) * CM))[lane];
    float s1 = v.x + v.y + v.z + v.w;
    float s2 = v.x * v.x + v.y * v.y + v.z * v.z + v.w * v.w;
#pragma unroll
    for (int off = 32; off; off >>= 1) {
      s1 += __shfl_xor(s1, off);
      s2 += __shfl_xor(s2, off);
    }
    float mu = s1 * (1.0f / 256.0f);
    float var = s2 * (1.0f / 256.0f) - mu * mu;
    float rs = rsqrtf(var + 1e-5f);
    float4 w4 = ((const float4*)lnw)[lane];
    float4 b4 = ((const float4*)lnb)[lane];
    ushort4 h;
    h.x = f2bf((v.x - mu) * rs * w4.x + b4.x);
    h.y = f2bf((v.y - mu) * rs * w4.y + b4.y);
    h.z = f2bf((v.z - mu) * rs * w4.z + b4.z);
    h.w = f2bf((v.w - mu) * rs * w4.w + b4.w);
    *(ushort4*)&xn[s * 264 + lane * 4] = h;
  }
  __syncthreads();

  f32x4 acc[4];
#pragma unroll
  for (int nt = 0; nt < 4; ++nt) acc[nt] = (f32x4){0.f, 0.f, 0.f, 0.f};
#pragma unroll
  for (int ks = 0; ks < 8; ++ks) {
    short8 af = *(const short8*)&xn[(ww * 16 + ln) * 264 + ks * 32 + qd * 8];
#pragma unroll
    for (int nt = 0; nt < 4; ++nt) {
      short8 bf = *(const short8*)(wlrT + (nt * 16 + ln) * 256 + ks * 32 + qd * 8);
      acc[nt] = __builtin_amdgcn_mfma_f32_16x16x32_bf16(af, bf, acc[nt], 0, 0, 0);
    }
  }
#pragma unroll
  for (int nt = 0; nt < 4; ++nt) {
    int c64 = nt * 16 + ln;
    float bias = (c64 < CC) ? bl[c64] : br[c64 - CC];
    ushort4 h;
    h.x = f2bf(acc[nt][0] + bias);
    h.y = f2bf(acc[nt][1] + bias);
    h.z = f2bf(acc[nt][2] + bias);
    h.w = f2bf(acc[nt][3] + bias);
    *(ushort4*)&sT[c64 * 136 + ww * 16 + qd * 4] = h;
  }
  __syncthreads();

  // A2 fragment store: wave job (rtloc = ww>>2, ks4 = ww&3); rt = 2*i + rtloc
  {
    int rtloc = ww >> 2, ks4 = ww & 3;
    short8 v = *(const short8*)&sT[(rtloc * 16 + ln) * 136 + ks4 * 32 + qd * 8];
    *(short8*)(A2 + ((size_t)(((2 * i + rtloc) * 4 + ks4) * 64 + lane)) * 8) = v;
  }
  // B row-major store
  {
    int row = tid >> 4, ch = tid & 15;
    short8 v = *(const short8*)&sT[(CC + row) * 136 + ch * 8];
    *(short8*)(Bbuf + ((size_t)(i * CC + row)) * SDIM + ch * 8) = v;
  }
}

// ---------------- kernel 2: fused outer-product + output projection ----------------
// Block = 8i x 8j = 64 pairs, 1024 threads (16 waves), 1024 blocks.
// p1 (16 waves, wy4 x wx4): P[256][256] = A@B^T, K=128; A-frags global (A2), B from LDS.
// P -> sP bf16 full-kappa (64 pairs x 1024), 2-way-free swizzle (overlays sB).
// p2 (8 waves = 2 ztq x 4 kq): out^T-swap mfma(W,P) -> D[z][p]; z-contiguous f32x4.
// kq 4-way partials reduced via LDS f32 (overlays sP), b128 out stores.
__global__ __launch_bounds__(1024) void k_main(
    const unsigned short* __restrict__ A2, const unsigned short* __restrict__ Bbuf,
    const unsigned short* __restrict__ WF, const float* __restrict__ bout,
    float* __restrict__ out) {
  extern __shared__ __align__(16) char lds[];
  unsigned short* sB = (unsigned short*)lds;   // [256][136] = 69,632 B
  unsigned short* sP = (unsigned short*)lds;   // [64][1032] = 132,096 B (overlay after p1)
  float* redF = (float*)lds;                   // [4 slots][64 p][68] f32 = 69,632 B (overlay)
  int tid = threadIdx.x;
  int lane = tid & 63, ww = tid >> 6;
  int qd = lane >> 4, ln = lane & 15;
  int i0 = blockIdx.x * 8, j0 = blockIdx.y * 8;

  // stage B tile: rows j0*32 .. +255, K=128
#pragma unroll
  for (int t = 0; t < 4; ++t) {
    int idx = tid + t * 1024;
    int r = idx >> 4, ch = idx & 15;
    short8 v = *(const short8*)(Bbuf + (size_t)(j0 * CC + r) * SDIM + ch * 8);
    *(short8*)&sB[r * 136 + ch * 8] = v;
  }
  __syncthreads();

  // phase 1: wave (wy=ww>>2, wx=ww&3): 64x64 region, A-frags from global
  int wy = ww >> 2, wx = ww & 3;
  f32x4 acc1[4][4];
#pragma unroll
  for (int a = 0; a < 4; ++a)
#pragma unroll
    for (int b = 0; b < 4; ++b) acc1[a][b] = (f32x4){0.f, 0.f, 0.f, 0.f};
#pragma unroll
  for (int ks = 0; ks < 4; ++ks) {
    short8 af[4];
#pragma unroll
    for (int ti = 0; ti < 4; ++ti)
      af[ti] = *(const short8*)(A2 + ((size_t)((i0 * 2 + wy * 4 + ti) * 4 + ks) * 64 + lane) * 8);
#pragma unroll
    for (int tj = 0; tj < 4; ++tj) {
      short8 bf = *(const short8*)&sB[(wx * 64 + tj * 16 + ln) * 136 + ks * 32 + qd * 8];
#pragma unroll
      for (int ti = 0; ti < 4; ++ti)
        acc1[ti][tj] = __builtin_amdgcn_mfma_f32_16x16x32_bf16(af[ti], bf, acc1[ti][tj], 0, 0, 0);
    }
  }
  __syncthreads();  // all sB reads done; sP overlay safe

  // P write: shorts offset p*1032 + d*32 + (((d>>1)&3)^cb)*8 + (cbase&7)
#pragma unroll
  for (int ti = 0; ti < 4; ++ti) {
    int iloc = wy * 2 + (ti >> 1);
    int cbase = 16 * (ti & 1) + qd * 4;
    int cb = cbase >> 3;
#pragma unroll
    for (int tj = 0; tj < 4; ++tj) {
      int jloc = wx * 2 + (tj >> 1);
      int d = 16 * (tj & 1) + ln;
      int p = iloc * 8 + jloc;
      uint2 u;
      u.x = pack_bf2(acc1[ti][tj][0], acc1[ti][tj][1]);
      u.y = pack_bf2(acc1[ti][tj][2], acc1[ti][tj][3]);
      *(uint2*)&sP[p * 1032 + d * 32 + ((((d >> 1) & 3) ^ cb) * 8) + (cbase & 7)] = u;
    }
  }
  __syncthreads();

  // phase 2 (waves 0..7): ztq = ww&1 (4 zt each), kq = ww>>1 (8 kappa-chunks each)
  int ztq = ww & 1, kq = ww >> 1;
  f32x4 acc2[4][4];  // [z4][mt]
#pragma unroll
  for (int a = 0; a < 4; ++a)
#pragma unroll
    for (int b = 0; b < 4; ++b) acc2[a][b] = (f32x4){0.f, 0.f, 0.f, 0.f};
  if (ww < 8) {
#pragma unroll
    for (int cc = 0; cc < 8; ++cc) {
      int ks = kq * 8 + cc;
      short8 afr[4];
#pragma unroll
      for (int mt = 0; mt < 4; ++mt)
        afr[mt] = *(const short8*)&sP[(mt * 16 + ln) * 1032 + ks * 32 + ((((ks >> 1) & 3) ^ qd) * 8)];
#pragma unroll
      for (int z4 = 0; z4 < 4; ++z4) {
        int zt = ztq * 4 + z4;
        short8 bfr = *(const short8*)(WF + ((size_t)(zt * 32 + ks) * 64 + lane) * 8);
#pragma unroll
        for (int mt = 0; mt < 4; ++mt)  // SWAPPED operands: D[m=z][n=p]
          acc2[z4][mt] = __builtin_amdgcn_mfma_f32_16x16x32_bf16(bfr, afr[mt], acc2[z4][mt], 0, 0, 0);
      }
    }
  }

  // kq 4-way reduction via LDS f32 (z-contiguous f32x4), slots overlay sP
  __syncthreads();  // all sP reads done
  if (ww < 8 && kq >= 2) {
    int s = (kq - 2) * 2 + ztq;
#pragma unroll
    for (int z4 = 0; z4 < 4; ++z4)
#pragma unroll
      for (int mt = 0; mt < 4; ++mt)
        *(f32x4*)&redF[(s * 64 + mt * 16 + ln) * 68 + z4 * 16 + qd * 4] = acc2[z4][mt];
  }
  __syncthreads();
  if (ww < 8 && kq < 2) {
    int s = kq * 2 + ztq;
#pragma unroll
    for (int z4 = 0; z4 < 4; ++z4)
#pragma unroll
      for (int mt = 0; mt < 4; ++mt)
        acc2[z4][mt] += *(const f32x4*)&redF[(s * 64 + mt * 16 + ln) * 68 + z4 * 16 + qd * 4];
  }
  __syncthreads();
  if (ww < 8 && kq == 1) {
#pragma unroll
    for (int z4 = 0; z4 < 4; ++z4)
#pragma unroll
      for (int mt = 0; mt < 4; ++mt)
        *(f32x4*)&redF[(ztq * 64 + mt * 16 + ln) * 68 + z4 * 16 + qd * 4] = acc2[z4][mt];
  }
  __syncthreads();
  if (ww < 8 && kq == 0) {
#pragma unroll
    for (int z4 = 0; z4 < 4; ++z4) {
      int z = (ztq * 4 + z4) * 16 + qd * 4;
      f32x4 bz = *(const f32x4*)(bout + z);
#pragma unroll
      for (int mt = 0; mt < 4; ++mt) {
        int p = mt * 16 + ln;
        f32x4 v = acc2[z4][mt] + *(const f32x4*)&redF[(ztq * 64 + p) * 68 + z4 * 16 + qd * 4] + bz;
        int i = i0 + (p >> 3), j = j0 + (p & 7);
        *(f32x4*)&out[((size_t)i * IDIM + j) * CZ + z] = v;
      }
    }
  }
}

extern "C" void kernel_launch(void* const* d_in, const int* in_sizes, int n_in,
                              void* d_out, int out_size, void* d_ws, size_t ws_size,
                              hipStream_t stream) {
  const float* msa = (const float*)d_in[0];
  const float* lnw = (const float*)d_in[1];
  const float* lnb = (const float*)d_in[2];
  const float* wl  = (const float*)d_in[3];
  const float* bl  = (const float*)d_in[4];
  const float* wr  = (const float*)d_in[5];
  const float* br  = (const float*)d_in[6];
  const float* wo  = (const float*)d_in[7];
  const float* bo  = (const float*)d_in[8];
  float* out = (float*)d_out;

  char* ws = (char*)d_ws;
  unsigned short* A2   = (unsigned short*)ws;                         // 2 MB (frag-major)
  unsigned short* Bbuf = (unsigned short*)(ws + (2u << 20));          // 2 MB (row-major)
  unsigned short* wlrT = (unsigned short*)(ws + (4u << 20));          // 32 KB
  unsigned short* WF   = (unsigned short*)(ws + (4u << 20) + 32768);  // 256 KB

  (void)hipFuncSetAttribute((const void*)k_lnproj,
                            hipFuncAttributeMaxDynamicSharedMemorySize, 84992);
  (void)hipFuncSetAttribute((const void*)k_main,
                            hipFuncAttributeMaxDynamicSharedMemorySize, 132096);

  k_prep<<<128, 256, 0, stream>>>(wl, wr, wo, wlrT, WF);
  k_lnproj<<<256, 512, 84992, stream>>>(msa, lnw, lnb, bl, br, wlrT, A2, Bbuf);
  k_main<<<dim3(32, 32), 1024, 132096, stream>>>(A2, Bbuf, WF, bo, out);
}

// Round 7
// 141.618 us; speedup vs baseline: 1.1099x; 1.1099x over previous
//
#include <hip/hip_runtime.h>

typedef __attribute__((ext_vector_type(8))) short short8;
typedef __attribute__((ext_vector_type(4))) float f32x4;

#define CM 256
#define CC 32
#define CZ 128
#define SDIM 128
#define IDIM 256

__device__ __forceinline__ unsigned short f2bf(float f) {
  union { float f; unsigned u; } v; v.f = f;
  unsigned r = v.u + 0x7fffu + ((v.u >> 16) & 1u);
  return (unsigned short)(r >> 16);
}
// pack two f32 -> two bf16 (round-half-up)
__device__ __forceinline__ unsigned pack_bf2(float a, float b) {
  union { float f; unsigned u; } x, y; x.f = a; y.f = b;
  return ((x.u + 0x8000u) >> 16) | ((y.u + 0x8000u) & 0xffff0000u);
}

// ---------------- kernel 0: weight prep ----------------
// wlrT2 fragment-major: wlrT2[((nt*8+ks)*64+lane)*8+e] = Wlr[c64=nt*16+ln][cm=ks*32+qd*8+e]
//   (c64<32: w_left col, else w_right col)
// WF fragment-major: WF[((zt*32+ks)*64+lane)*8+e]; lane(qd,ln) holds
//   W[z=zt*16+ln][kappa=ks*32+qd*8+e]/128, kappa=d*32+c (d=ks, c=qd*8+e)
__global__ void k_prep(const float* __restrict__ wl, const float* __restrict__ wr,
                       const float* __restrict__ wo,
                       unsigned short* __restrict__ wlrT2, unsigned short* __restrict__ WF) {
  int t = blockIdx.x * 256 + threadIdx.x;
  if (t < 2048) {
    int frag = t >> 6, lane = t & 63;
    int nt = frag >> 3, ks = frag & 7;
    int ln = lane & 15, qd = lane >> 4;
    int c64 = nt * 16 + ln;
#pragma unroll
    for (int e = 0; e < 8; ++e) {
      int cm = ks * 32 + qd * 8 + e;
      float v = (c64 < CC) ? wl[cm * CC + c64] : wr[cm * CC + (c64 - CC)];
      wlrT2[(size_t)t * 8 + e] = f2bf(v);
    }
  } else {
    int t2 = t - 2048;
    if (t2 < 8 * 32 * 64) {
      int zt = t2 >> 11, ks = (t2 >> 6) & 31, lane = t2 & 63;
      int ln = lane & 15, qd = lane >> 4;
      int z = zt * 16 + ln;
#pragma unroll
      for (int e = 0; e < 8; ++e) {
        int c = qd * 8 + e, d = ks;
        WF[(size_t)t2 * 8 + e] = f2bf(wo[(c * 32 + d) * CZ + z] * (1.0f / 128.0f));
      }
    }
  }
}

// ---------------- kernel 1: LayerNorm + dual projection ----------------
// Block (i, sh): 512 blocks x 256 threads (4 waves); s-range = [sh*64, +64).
// Outputs:
//   A2 fragment-major: A2[((rt*4+ks)*64+lane)*8+e] = A[rt*16+ln][s=ks*32+qd*8+e]
//     (A rows = i*32+c flattened; rt = row/16)
//   Bbuf row-major:    Bbuf[(i*32+d)*128 + s]
__global__ __launch_bounds__(256) void k_lnproj(
    const float* __restrict__ x, const float* __restrict__ lnw, const float* __restrict__ lnb,
    const float* __restrict__ bl, const float* __restrict__ br,
    const unsigned short* __restrict__ wlrT2,
    unsigned short* __restrict__ A2, unsigned short* __restrict__ Bbuf) {
  __shared__ __align__(16) unsigned short xn[64][264];  // 33,792 B
  __shared__ __align__(16) unsigned short sT[64][72];   //  9,216 B
  int tid = threadIdx.x;
  int lane = tid & 63, ww = tid >> 6;      // 4 waves
  int qd = lane >> 4, ln = lane & 15;
  int i = blockIdx.x, sh = blockIdx.y;

  // LN: wave ww handles local rows ww*16 .. +15 (global s = sh*64 + local)
  for (int rr = 0; rr < 16; ++rr) {
    int sl = ww * 16 + rr;
    int s = sh * 64 + sl;
    float4 v = ((const float4*)(x + ((size_t)s * IDIM + i) * CM))[lane];
    float s1 = v.x + v.y + v.z + v.w;
    float s2 = v.x * v.x + v.y * v.y + v.z * v.z + v.w * v.w;
#pragma unroll
    for (int off = 32; off; off >>= 1) {
      s1 += __shfl_xor(s1, off);
      s2 += __shfl_xor(s2, off);
    }
    float mu = s1 * (1.0f / 256.0f);
    float var = s2 * (1.0f / 256.0f) - mu * mu;
    float rs = rsqrtf(var + 1e-5f);
    float4 w4 = ((const float4*)lnw)[lane];
    float4 b4 = ((const float4*)lnb)[lane];
    ushort4 h;
    h.x = f2bf((v.x - mu) * rs * w4.x + b4.x);
    h.y = f2bf((v.y - mu) * rs * w4.y + b4.y);
    h.z = f2bf((v.z - mu) * rs * w4.z + b4.z);
    h.w = f2bf((v.w - mu) * rs * w4.w + b4.w);
    *(ushort4*)&xn[sl][lane * 4] = h;
  }
  __syncthreads();

  // project: wave ww = m-tile (16 local s-rows), all 4 n-tiles, K=256
  f32x4 acc[4];
#pragma unroll
  for (int nt = 0; nt < 4; ++nt) acc[nt] = (f32x4){0.f, 0.f, 0.f, 0.f};
#pragma unroll
  for (int ks = 0; ks < 8; ++ks) {
    short8 af = *(const short8*)&xn[ww * 16 + ln][ks * 32 + qd * 8];
#pragma unroll
    for (int nt = 0; nt < 4; ++nt) {
      short8 bf = *(const short8*)(wlrT2 + ((size_t)((nt * 8 + ks) * 64 + lane)) * 8);
      acc[nt] = __builtin_amdgcn_mfma_f32_16x16x32_bf16(af, bf, acc[nt], 0, 0, 0);
    }
  }
  // C layout: col(c64)=ln, row(s-local)=qd*4+rg. Bias, transpose via sT[c64][s-local].
#pragma unroll
  for (int nt = 0; nt < 4; ++nt) {
    int c64 = nt * 16 + ln;
    float bias = (c64 < CC) ? bl[c64] : br[c64 - CC];
    ushort4 h;
    h.x = f2bf(acc[nt][0] + bias);
    h.y = f2bf(acc[nt][1] + bias);
    h.z = f2bf(acc[nt][2] + bias);
    h.w = f2bf(acc[nt][3] + bias);
    *(ushort4*)&sT[c64][ww * 16 + qd * 4] = h;
  }
  __syncthreads();

  // A2 fragment store: wave ww -> (rtloc = ww>>1, ksl = ww&1); global rt = 2*i + rtloc,
  // global ks = sh*2 + ksl
  {
    int rtloc = ww >> 1, ksl = ww & 1;
    short8 v = *(const short8*)&sT[rtloc * 16 + ln][ksl * 32 + qd * 8];
    *(short8*)(A2 + ((size_t)(((2 * i + rtloc) * 4 + (sh * 2 + ksl)) * 64 + lane)) * 8) = v;
  }
  // B row-major store: 32 rows x 8 chunks (16B)
  {
    int row = tid >> 3, ch = tid & 7;
    short8 v = *(const short8*)&sT[CC + row][ch * 8];
    *(short8*)(Bbuf + ((size_t)(i * CC + row)) * SDIM + sh * 64 + ch * 8) = v;
  }
}

// ---------------- kernel 2: fused outer-product + output projection ----------------
// Block = 8i x 8j = 64 pairs, 1024 threads (16 waves), 1024 blocks.
// p1 (16 waves, wy4 x wx4): P[256][256] = A@B^T, K=128; A-frags global (A2), B from LDS.
// P -> sP bf16 full-kappa (64 pairs x 1024), 2-way swizzle (overlays sB).
// p2 (ALL 16 waves = 4 ztp x 4 kq): operand-swapped mfma(W,P) -> D[z][p].
// kq 4-way partials reduced via lane-linear LDS f32 (conflict-free, overlays sP).
__global__ __launch_bounds__(1024) void k_main(
    const unsigned short* __restrict__ A2, const unsigned short* __restrict__ Bbuf,
    const unsigned short* __restrict__ WF, const float* __restrict__ bout,
    float* __restrict__ out) {
  extern __shared__ __align__(16) char lds[];
  unsigned short* sB = (unsigned short*)lds;   // [256][136] = 69,632 B
  unsigned short* sP = (unsigned short*)lds;   // [64][1032] = 132,096 B (overlay after p1)
  float* redR = (float*)lds;                   // lane-linear slots, 8 x 8 KB (overlay)
  int tid = threadIdx.x;
  int lane = tid & 63, ww = tid >> 6;
  int qd = lane >> 4, ln = lane & 15;
  int i0 = blockIdx.x * 8, j0 = blockIdx.y * 8;

  // stage B tile: rows j0*32 .. +255, K=128
#pragma unroll
  for (int t = 0; t < 4; ++t) {
    int idx = tid + t * 1024;
    int r = idx >> 4, ch = idx & 15;
    short8 v = *(const short8*)(Bbuf + (size_t)(j0 * CC + r) * SDIM + ch * 8);
    *(short8*)&sB[r * 136 + ch * 8] = v;
  }
  __syncthreads();

  // phase 1: wave (wy=ww>>2, wx=ww&3): 64x64 region, A-frags from global
  int wy = ww >> 2, wx = ww & 3;
  f32x4 acc1[4][4];
#pragma unroll
  for (int a = 0; a < 4; ++a)
#pragma unroll
    for (int b = 0; b < 4; ++b) acc1[a][b] = (f32x4){0.f, 0.f, 0.f, 0.f};
#pragma unroll
  for (int ks = 0; ks < 4; ++ks) {
    short8 af[4];
#pragma unroll
    for (int ti = 0; ti < 4; ++ti)
      af[ti] = *(const short8*)(A2 + ((size_t)((i0 * 2 + wy * 4 + ti) * 4 + ks) * 64 + lane) * 8);
#pragma unroll
    for (int tj = 0; tj < 4; ++tj) {
      short8 bf = *(const short8*)&sB[(wx * 64 + tj * 16 + ln) * 136 + ks * 32 + qd * 8];
#pragma unroll
      for (int ti = 0; ti < 4; ++ti)
        acc1[ti][tj] = __builtin_amdgcn_mfma_f32_16x16x32_bf16(af[ti], bf, acc1[ti][tj], 0, 0, 0);
    }
  }
  __syncthreads();  // all sB reads done; sP overlay safe

  // P write: shorts offset p*1032 + d*32 + (((d>>1)&3)^cb)*8 + (cbase&7)
#pragma unroll
  for (int ti = 0; ti < 4; ++ti) {
    int iloc = wy * 2 + (ti >> 1);
    int cbase = 16 * (ti & 1) + qd * 4;
    int cb = cbase >> 3;
#pragma unroll
    for (int tj = 0; tj < 4; ++tj) {
      int jloc = wx * 2 + (tj >> 1);
      int d = 16 * (tj & 1) + ln;
      int p = iloc * 8 + jloc;
      uint2 u;
      u.x = pack_bf2(acc1[ti][tj][0], acc1[ti][tj][1]);
      u.y = pack_bf2(acc1[ti][tj][2], acc1[ti][tj][3]);
      *(uint2*)&sP[p * 1032 + d * 32 + ((((d >> 1) & 3) ^ cb) * 8) + (cbase & 7)] = u;
    }
  }
  __syncthreads();

  // phase 2: ALL 16 waves. ztp = ww&3 (zt in {2ztp, 2ztp+1}), kq = ww>>2 (8 ks each)
  int ztp = ww & 3, kq = ww >> 2;
  f32x4 acc2[2][4];  // [h2][mt]
#pragma unroll
  for (int a = 0; a < 2; ++a)
#pragma unroll
    for (int b = 0; b < 4; ++b) acc2[a][b] = (f32x4){0.f, 0.f, 0.f, 0.f};
#pragma unroll
  for (int cc = 0; cc < 8; ++cc) {
    int ks = kq * 8 + cc;
    short8 afr[4];
#pragma unroll
    for (int mt = 0; mt < 4; ++mt)
      afr[mt] = *(const short8*)&sP[(mt * 16 + ln) * 1032 + ks * 32 + ((((ks >> 1) & 3) ^ qd) * 8)];
#pragma unroll
    for (int h2 = 0; h2 < 2; ++h2) {
      int zt = ztp * 2 + h2;
      short8 bfr = *(const short8*)(WF + ((size_t)(zt * 32 + ks) * 64 + lane) * 8);
#pragma unroll
      for (int mt = 0; mt < 4; ++mt)  // SWAPPED operands: D[m=z][n=p]
        acc2[h2][mt] = __builtin_amdgcn_mfma_f32_16x16x32_bf16(bfr, afr[mt], acc2[h2][mt], 0, 0, 0);
    }
  }

  // kq 4-way reduction, lane-linear slots (zero bank conflicts):
  //   slot(s): redR[(((s*2+h2)*4+mt)<<8) + lane*4 .. +3]
  __syncthreads();  // all sP reads done
  if (kq >= 2) {
    int s = (kq - 2) * 4 + ztp;
#pragma unroll
    for (int h2 = 0; h2 < 2; ++h2)
#pragma unroll
      for (int mt = 0; mt < 4; ++mt)
        *(f32x4*)&redR[(((s * 2 + h2) * 4 + mt) << 8) + lane * 4] = acc2[h2][mt];
  }
  __syncthreads();
  if (kq < 2) {
    int s = kq * 4 + ztp;
#pragma unroll
    for (int h2 = 0; h2 < 2; ++h2)
#pragma unroll
      for (int mt = 0; mt < 4; ++mt)
        acc2[h2][mt] += *(const f32x4*)&redR[(((s * 2 + h2) * 4 + mt) << 8) + lane * 4];
  }
  __syncthreads();
  if (kq == 1) {
    int s = ztp;
#pragma unroll
    for (int h2 = 0; h2 < 2; ++h2)
#pragma unroll
      for (int mt = 0; mt < 4; ++mt)
        *(f32x4*)&redR[(((s * 2 + h2) * 4 + mt) << 8) + lane * 4] = acc2[h2][mt];
  }
  __syncthreads();
  if (kq == 0) {
    int s = ztp;
#pragma unroll
    for (int h2 = 0; h2 < 2; ++h2) {
      int z = (ztp * 2 + h2) * 16 + qd * 4;
      f32x4 bz = *(const f32x4*)(bout + z);
#pragma unroll
      for (int mt = 0; mt < 4; ++mt) {
        int p = mt * 16 + ln;
        f32x4 v = acc2[h2][mt] +
                  *(const f32x4*)&redR[(((s * 2 + h2) * 4 + mt) << 8) + lane * 4] + bz;
        int i = i0 + (p >> 3), j = j0 + (p & 7);
        *(f32x4*)&out[((size_t)i * IDIM + j) * CZ + z] = v;
      }
    }
  }
}

extern "C" void kernel_launch(void* const* d_in, const int* in_sizes, int n_in,
                              void* d_out, int out_size, void* d_ws, size_t ws_size,
                              hipStream_t stream) {
  const float* msa = (const float*)d_in[0];
  const float* lnw = (const float*)d_in[1];
  const float* lnb = (const float*)d_in[2];
  const float* wl  = (const float*)d_in[3];
  const float* bl  = (const float*)d_in[4];
  const float* wr  = (const float*)d_in[5];
  const float* br  = (const float*)d_in[6];
  const float* wo  = (const float*)d_in[7];
  const float* bo  = (const float*)d_in[8];
  float* out = (float*)d_out;

  char* ws = (char*)d_ws;
  unsigned short* A2    = (unsigned short*)ws;                         // 2 MB (frag-major)
  unsigned short* Bbuf  = (unsigned short*)(ws + (2u << 20));          // 2 MB (row-major)
  unsigned short* wlrT2 = (unsigned short*)(ws + (4u << 20));          // 32 KB (frag-major)
  unsigned short* WF    = (unsigned short*)(ws + (4u << 20) + 32768);  // 256 KB

  (void)hipFuncSetAttribute((const void*)k_main,
                            hipFuncAttributeMaxDynamicSharedMemorySize, 132096);

  k_prep<<<72, 256, 0, stream>>>(wl, wr, wo, wlrT2, WF);
  k_lnproj<<<dim3(256, 2), 256, 0, stream>>>(msa, lnw, lnb, bl, br, wlrT2, A2, Bbuf);
  k_main<<<dim3(32, 32), 1024, 132096, stream>>>(A2, Bbuf, WF, bo, out);
}